// Round 2
// baseline (235.881 us; speedup 1.0000x reference)
//
#include <hip/hip_runtime.h>
#include <hip/hip_bf16.h>

// Problem constants
#define NROWS 16384          // B*T
#define FDIM  512            // K
#define GE    640            // G*E
#define EDIM  320
#define DDIM  384
#define CB_OFF 12582912      // 16384*768
#define SCAL_OFF 23068672    // CB_OFF + 16384*640

#define BM 128
#define BN 64
#define BK 32
#define LDA 132   // BM+4 floats
#define LDB 68    // BN+4 floats

// ---------------- init accumulators ----------------
__global__ void vq_init_k(float* acc) {
    int i = blockIdx.x * 256 + threadIdx.x;
    if (i < 1280) acc[i] = 0.0f;
}

// ---------------- GEMM: logits = X @ W^T + b ----------------
// X: (16384,512) rm, W: (640,512) rm, L: (16384,640)
// 256 threads, 8x4 microtile, register-prefetch double buffering.
__global__ __launch_bounds__(256) void gemm_logits_k(
    const float* __restrict__ X, const float* __restrict__ W,
    const float* __restrict__ bias, float* __restrict__ L)
{
    __shared__ float As[BK][LDA];   // [k][m]
    __shared__ float Bs[BK][LDB];   // [k][n]

    const int tid = threadIdx.x;
    const int tm = tid >> 4;        // 0..15 -> rows tm*8..tm*8+7
    const int tn = tid & 15;        // 0..15 -> cols tn*4..tn*4+3
    const int row0 = blockIdx.x * BM;
    const int col0 = blockIdx.y * BN;

    // staging maps (coalesced float4 global loads)
    const int ar = tid >> 1;        // 0..127
    const int ac = (tid & 1) * 16;  // 0 or 16
    const int br = tid >> 2;        // 0..63
    const int bc = (tid & 3) * 8;   // 0,8,16,24

    const float* aptr = X + (size_t)(row0 + ar) * FDIM + ac;
    const float* bptr = W + (size_t)(col0 + br) * FDIM + bc;

    float4 pa[4], pb[2];
    pa[0] = *(const float4*)(aptr + 0);
    pa[1] = *(const float4*)(aptr + 4);
    pa[2] = *(const float4*)(aptr + 8);
    pa[3] = *(const float4*)(aptr + 12);
    pb[0] = *(const float4*)(bptr + 0);
    pb[1] = *(const float4*)(bptr + 4);

    float acc[8][4] = {};

    #pragma unroll 1
    for (int t = 0; t < FDIM / BK; ++t) {
        // write staged regs to LDS (transpose to [k][m])
        #pragma unroll
        for (int q = 0; q < 4; ++q) {
            As[ac + q * 4 + 0][ar] = pa[q].x;
            As[ac + q * 4 + 1][ar] = pa[q].y;
            As[ac + q * 4 + 2][ar] = pa[q].z;
            As[ac + q * 4 + 3][ar] = pa[q].w;
        }
        #pragma unroll
        for (int q = 0; q < 2; ++q) {
            Bs[bc + q * 4 + 0][br] = pb[q].x;
            Bs[bc + q * 4 + 1][br] = pb[q].y;
            Bs[bc + q * 4 + 2][br] = pb[q].z;
            Bs[bc + q * 4 + 3][br] = pb[q].w;
        }
        __syncthreads();

        // prefetch next k-tile into registers (hides HBM latency under compute)
        if (t + 1 < FDIM / BK) {
            const float* ap = aptr + (t + 1) * BK;
            const float* bp = bptr + (t + 1) * BK;
            pa[0] = *(const float4*)(ap + 0);
            pa[1] = *(const float4*)(ap + 4);
            pa[2] = *(const float4*)(ap + 8);
            pa[3] = *(const float4*)(ap + 12);
            pb[0] = *(const float4*)(bp + 0);
            pb[1] = *(const float4*)(bp + 4);
        }

        #pragma unroll
        for (int k = 0; k < BK; ++k) {
            float a[8], b[4];
            *(float4*)&a[0] = *(const float4*)&As[k][tm * 8];
            *(float4*)&a[4] = *(const float4*)&As[k][tm * 8 + 4];
            *(float4*)&b[0] = *(const float4*)&Bs[k][tn * 4];
            #pragma unroll
            for (int i = 0; i < 8; ++i)
                #pragma unroll
                for (int j = 0; j < 4; ++j)
                    acc[i][j] += a[i] * b[j];
        }
        __syncthreads();
    }

    const float4 bv = *(const float4*)&bias[col0 + tn * 4];
    #pragma unroll
    for (int i = 0; i < 8; ++i) {
        const int row = row0 + tm * 8 + i;
        float4 v;
        v.x = acc[i][0] + bv.x;
        v.y = acc[i][1] + bv.y;
        v.z = acc[i][2] + bv.z;
        v.w = acc[i][3] + bv.w;
        *(float4*)&L[(size_t)row * GE + col0 + tn * 4] = v;
    }
}

// ---------------- per-(n,g) epilogue ----------------
// One wave handles 8 (n,g) pairs (same g, rows strided by 2048), with
// register prefetch of the next row. L aliases the cb output region.
__global__ __launch_bounds__(256) void vq_rows_k(
    float* __restrict__ Lcb,                 // logits in, cb out (same region)
    const float* __restrict__ gumbel,
    const float* __restrict__ entries,
    float* __restrict__ out,                 // d_out base (quantized at 0)
    float* __restrict__ hard_acc,            // ws[0..640)
    float* __restrict__ soft_acc)            // ws[640..1280)
{
    const int tid  = threadIdx.x;
    const int lane = tid & 63;
    const int w    = blockIdx.x * 4 + (tid >> 6);   // 0..4095
    const int g    = w >> 11;                        // 0/1
    const int nb   = w & 2047;

    float racc[5] = {0.f, 0.f, 0.f, 0.f, 0.f};
    float hacc[5] = {0.f, 0.f, 0.f, 0.f, 0.f};

    float l[5], gu[5], l2[5], gu2[5];
    {
        const float* lrow = Lcb + (size_t)nb * GE + g * EDIM;
        const float* grow = gumbel + ((size_t)nb * 2 + g) * EDIM;
        #pragma unroll
        for (int j = 0; j < 5; ++j) {
            l[j]  = lrow[lane + j * 64];
            gu[j] = grow[lane + j * 64];
        }
    }

    #pragma unroll 1
    for (int i = 0; i < 8; ++i) {
        const int n = nb + (i << 11);
        // prefetch next row
        if (i < 7) {
            const int n2 = nb + ((i + 1) << 11);
            const float* lrow2 = Lcb + (size_t)n2 * GE + g * EDIM;
            const float* grow2 = gumbel + ((size_t)n2 * 2 + g) * EDIM;
            #pragma unroll
            for (int j = 0; j < 5; ++j) {
                l2[j]  = lrow2[lane + j * 64];
                gu2[j] = grow2[lane + j * 64];
            }
        }

        float t[5];
        #pragma unroll
        for (int j = 0; j < 5; ++j)
            t[j] = (l[j] + gu[j]) * 0.5f;   // (logits+gumbel)/TAU, TAU=2

        // local argmax (first-index tie-break)
        float hv = l[0]; int hi = lane;
        float gv = t[0]; int gi = lane;
        #pragma unroll
        for (int j = 1; j < 5; ++j) {
            const int e = lane + j * 64;
            if (l[j] > hv) { hv = l[j]; hi = e; }
            if (t[j] > gv) { gv = t[j]; gi = e; }
        }
        #pragma unroll
        for (int off = 32; off > 0; off >>= 1) {
            float ov = __shfl_xor(hv, off); int oi = __shfl_xor(hi, off);
            if (ov > hv || (ov == hv && oi < hi)) { hv = ov; hi = oi; }
            float ov2 = __shfl_xor(gv, off); int oi2 = __shfl_xor(gi, off);
            if (ov2 > gv || (ov2 == gv && oi2 < gi)) { gv = ov2; gi = oi2; }
        }

        // softmax exps + sums
        float eh[5], eg[5];
        float sh = 0.f, sg = 0.f;
        #pragma unroll
        for (int j = 0; j < 5; ++j) {
            eh[j] = expf(l[j] - hv);
            eg[j] = expf(t[j] - gv);
            sh += eh[j]; sg += eg[j];
        }
        #pragma unroll
        for (int off = 32; off > 0; off >>= 1) {
            sh += __shfl_xor(sh, off);
            sg += __shfl_xor(sg, off);
        }
        const float ish = 1.0f / sh;
        const float isg = 1.0f / sg;

        // accumulate soft probs + hard counts; find y_soft at argmax
        float a_part = 0.f;
        #pragma unroll
        for (int j = 0; j < 5; ++j) {
            const int e = lane + j * 64;
            racc[j] += eh[j] * ish;
            if (e == hi) hacc[j] += 1.0f;
            if (e == gi) a_part = eg[j] * isg;
        }
        #pragma unroll
        for (int off = 32; off > 0; off >>= 1) a_part += __shfl_xor(a_part, off);
        const float yv = (1.0f - a_part) + a_part;   // straight-through value

        // cb write (overwrites logits slice in place)
        float* lrow = Lcb + (size_t)n * GE + g * EDIM;
        #pragma unroll
        for (int j = 0; j < 5; ++j) {
            const int e = lane + j * 64;
            lrow[e] = (e == gi) ? yv : 0.0f;
        }

        // quantized write: yv * entries[g, gi, :]
        const float* ent = entries + ((size_t)(g * EDIM + gi)) * DDIM;
        float* qrow = out + (size_t)n * 768 + g * DDIM;
        #pragma unroll
        for (int jj = 0; jj < 6; ++jj) {
            const int d = lane + jj * 64;
            qrow[d] = yv * ent[d];
        }

        // rotate prefetched row in
        #pragma unroll
        for (int j = 0; j < 5; ++j) { l[j] = l2[j]; gu[j] = gu2[j]; }
    }

    #pragma unroll
    for (int j = 0; j < 5; ++j) {
        const int e = g * EDIM + lane + j * 64;
        atomicAdd(&hard_acc[e], hacc[j]);
        atomicAdd(&soft_acc[e], racc[j]);
    }
}

// ---------------- perplexities ----------------
__global__ void vq_final_k(const float* __restrict__ hard_acc,
                           const float* __restrict__ soft_acc,
                           float* __restrict__ out)
{
    const int lane = threadIdx.x & 63;
    float code = 0.f, prob = 0.f;
    for (int g = 0; g < 2; ++g) {
        float shh = 0.f, sss = 0.f;
        #pragma unroll
        for (int j = 0; j < 5; ++j) {
            const int e = g * EDIM + lane + j * 64;
            const float ph = hard_acc[e] * (1.0f / 16384.0f);
            const float ps = soft_acc[e] * (1.0f / 16384.0f);
            shh += ph * logf(ph + 1e-7f);
            sss += ps * logf(ps + 1e-7f);
        }
        #pragma unroll
        for (int off = 32; off > 0; off >>= 1) {
            shh += __shfl_xor(shh, off);
            sss += __shfl_xor(sss, off);
        }
        code += expf(-shh);
        prob += expf(-sss);
    }
    if (threadIdx.x == 0) {
        out[SCAL_OFF + 0] = code;
        out[SCAL_OFF + 1] = prob;
    }
}

extern "C" void kernel_launch(void* const* d_in, const int* in_sizes, int n_in,
                              void* d_out, int out_size, void* d_ws, size_t ws_size,
                              hipStream_t stream) {
    const float* x       = (const float*)d_in[0];
    const float* proj_w  = (const float*)d_in[1];
    const float* proj_b  = (const float*)d_in[2];
    const float* entries = (const float*)d_in[3];
    const float* gumbel  = (const float*)d_in[4];
    float* out = (float*)d_out;
    float* acc = (float*)d_ws;                 // 1280 floats
    float* logits = out + CB_OFF;              // stage logits in cb region

    hipLaunchKernelGGL(vq_init_k, dim3(5), dim3(256), 0, stream, acc);
    hipLaunchKernelGGL(gemm_logits_k, dim3(NROWS / BM, GE / BN), dim3(256), 0, stream,
                       x, proj_w, proj_b, logits);
    hipLaunchKernelGGL(vq_rows_k, dim3(1024), dim3(256), 0, stream,
                       logits, gumbel, entries, out, acc, acc + GE);
    hipLaunchKernelGGL(vq_final_k, dim3(1), dim3(64), 0, stream,
                       acc, acc + GE, out);
}

// Round 3
// 95.765 us; speedup vs baseline: 2.4631x; 2.4631x over previous
//
#include <hip/hip_runtime.h>
#include <hip/hip_bf16.h>

typedef unsigned short ushort_t;
typedef __attribute__((ext_vector_type(8))) short bf16x8;
typedef __attribute__((ext_vector_type(4))) float f32x4;

// Problem constants
#define NROWS 16384          // B*T
#define FDIM  512            // K
#define GE    640            // G*E
#define EDIM  320
#define DDIM  384
#define CB_OFF 12582912      // 16384*768
#define SCAL_OFF 23068672    // CB_OFF + 16384*640
// bf16 staging inside out[quantized region] (free until vq_rows)
#define XB_OFF 0             // 8388608 bf16 = 4194304 floats
#define WB_OFF 4194304       // floats; 327680 bf16 = 163840 floats

// ---------------- init accumulators ----------------
__global__ void vq_init_k(float* acc) {
    int i = blockIdx.x * 256 + threadIdx.x;
    if (i < 1280) acc[i] = 0.0f;
}

// ---------------- fp32 -> bf16 convert (RNE) ----------------
static __device__ __forceinline__ unsigned f2bf(float f) {
    unsigned u = __float_as_uint(f);
    return (u + 0x7FFFu + ((u >> 16) & 1u)) >> 16;
}

__global__ __launch_bounds__(256) void convert_bf16_k(
    const float* __restrict__ X, const float* __restrict__ W,
    ushort_t* __restrict__ Xb, ushort_t* __restrict__ Wb)
{
    const size_t i = (size_t)blockIdx.x * 256 + threadIdx.x;
    const float4* src;
    ushort_t* dst;
    if (i < 1048576) {                    // X: 8388608 elems / 8
        src = (const float4*)X + i * 2;
        dst = Xb + i * 8;
    } else {                              // W: 327680 elems / 8
        const size_t j = i - 1048576;
        src = (const float4*)W + j * 2;
        dst = Wb + j * 8;
    }
    const float4 v0 = src[0], v1 = src[1];
    uint4 o;
    o.x = f2bf(v0.x) | (f2bf(v0.y) << 16);
    o.y = f2bf(v0.z) | (f2bf(v0.w) << 16);
    o.z = f2bf(v1.x) | (f2bf(v1.y) << 16);
    o.w = f2bf(v1.z) | (f2bf(v1.w) << 16);
    *(uint4*)dst = o;
}

// ---------------- async global->LDS helper ----------------
static __device__ __forceinline__ void gload16(const void* g, void* l) {
    __builtin_amdgcn_global_load_lds(
        (const __attribute__((address_space(1))) unsigned int*)g,
        (__attribute__((address_space(3))) unsigned int*)l, 16, 0, 0);
}

// ---------------- MFMA GEMM: L = Xb @ Wb^T + b ----------------
// Xb (16384,512) bf16 rm, Wb (640,512) bf16 rm, L (16384,640) f32.
// 128x128 tile, BK=32, 4 waves (2x2), each wave 64x64 = 4x4 frags of 16x16x32.
__global__ __launch_bounds__(256) void gemm_mfma_k(
    const ushort_t* __restrict__ Xb, const ushort_t* __restrict__ Wb,
    const float* __restrict__ bias, float* __restrict__ L)
{
    __shared__ __align__(16) ushort_t As[128 * 32];   // [row][k], 64B/row
    __shared__ __align__(16) ushort_t Bs[128 * 32];

    const int tid  = threadIdx.x;
    const int lane = tid & 63;
    const int wv   = tid >> 6;          // 0..3
    const int wr   = (wv >> 1) * 64;    // wave row offset in tile
    const int wc   = (wv & 1) * 64;     // wave col offset in tile
    const int row0 = blockIdx.x * 128;
    const int col0 = blockIdx.y * 128;

    // staging: chunk c = tid (+256): row = c>>2, k-ofs = (c&3)*8
    const int c0r = tid >> 2;
    const int c0k = (tid & 3) * 8;

    f32x4 acc[4][4] = {};

    const int rA = lane & 15;
    const int kb = (lane >> 4) * 8;

    for (int t = 0; t < 16; ++t) {
        const int k0 = t * 32;
        gload16(Xb + (size_t)(row0 + c0r) * FDIM + k0 + c0k,        &As[tid * 8]);
        gload16(Xb + (size_t)(row0 + 64 + c0r) * FDIM + k0 + c0k,   &As[2048 + tid * 8]);
        gload16(Wb + (size_t)(col0 + c0r) * FDIM + k0 + c0k,        &Bs[tid * 8]);
        gload16(Wb + (size_t)(col0 + 64 + c0r) * FDIM + k0 + c0k,   &Bs[2048 + tid * 8]);
        __syncthreads();

        bf16x8 af[4], bfr[4];
        #pragma unroll
        for (int mi = 0; mi < 4; ++mi)
            af[mi] = *(const bf16x8*)&As[(wr + mi * 16 + rA) * 32 + kb];
        #pragma unroll
        for (int ni = 0; ni < 4; ++ni)
            bfr[ni] = *(const bf16x8*)&Bs[(wc + ni * 16 + rA) * 32 + kb];

        #pragma unroll
        for (int mi = 0; mi < 4; ++mi)
            #pragma unroll
            for (int ni = 0; ni < 4; ++ni)
                acc[mi][ni] = __builtin_amdgcn_mfma_f32_16x16x32_bf16(
                    af[mi], bfr[ni], acc[mi][ni], 0, 0, 0);
        __syncthreads();
    }

    // C/D map (guide-verified): col = lane&15, row = (lane>>4)*4 + reg
    const int colb = col0 + wc + (lane & 15);
    const int rowb = row0 + wr + (lane >> 4) * 4;
    #pragma unroll
    for (int ni = 0; ni < 4; ++ni) {
        const int col = colb + ni * 16;
        const float bv = bias[col];
        #pragma unroll
        for (int mi = 0; mi < 4; ++mi) {
            const int row = rowb + mi * 16;
            #pragma unroll
            for (int j = 0; j < 4; ++j)
                L[(size_t)(row + j) * GE + col] = acc[mi][ni][j] + bv;
        }
    }
}

// ---------------- per-(n,g) epilogue ----------------
// 2048 waves, 16 rows each (same g per block). L aliases the cb out region.
__global__ __launch_bounds__(256) void vq_rows_k(
    float* __restrict__ Lcb,                 // logits in, cb out (same region)
    const float* __restrict__ gumbel,
    const float* __restrict__ entries,
    float* __restrict__ out,                 // d_out base (quantized at 0)
    float* __restrict__ hard_acc,            // ws[0..640)
    float* __restrict__ soft_acc)            // ws[640..1280)
{
    __shared__ float redH[320], redS[320];

    const int tid  = threadIdx.x;
    const int lane = tid & 63;
    const int w    = blockIdx.x * 4 + (tid >> 6);   // 0..2047
    const int g    = w >> 10;                        // uniform per block
    const int nb   = w & 1023;

    for (int e = tid; e < 320; e += 256) { redH[e] = 0.f; redS[e] = 0.f; }

    float racc[5] = {0.f, 0.f, 0.f, 0.f, 0.f};
    float hacc[5] = {0.f, 0.f, 0.f, 0.f, 0.f};

    float l[5], gu[5], l2[5], gu2[5];
    {
        const float* lrow = Lcb + (size_t)nb * GE + g * EDIM;
        const float* grow = gumbel + ((size_t)nb * 2 + g) * EDIM;
        #pragma unroll
        for (int j = 0; j < 5; ++j) {
            l[j]  = lrow[lane + j * 64];
            gu[j] = grow[lane + j * 64];
        }
    }

    #pragma unroll 1
    for (int i = 0; i < 16; ++i) {
        const int n = nb + (i << 10);
        if (i < 15) {
            const int n2 = nb + ((i + 1) << 10);
            const float* lrow2 = Lcb + (size_t)n2 * GE + g * EDIM;
            const float* grow2 = gumbel + ((size_t)n2 * 2 + g) * EDIM;
            #pragma unroll
            for (int j = 0; j < 5; ++j) {
                l2[j]  = lrow2[lane + j * 64];
                gu2[j] = grow2[lane + j * 64];
            }
        }

        float t[5];
        #pragma unroll
        for (int j = 0; j < 5; ++j)
            t[j] = (l[j] + gu[j]) * 0.5f;   // (logits+gumbel)/TAU, TAU=2

        // local argmax (first-index tie-break)
        float hv = l[0]; int hi = lane;
        float gv = t[0]; int gi = lane;
        #pragma unroll
        for (int j = 1; j < 5; ++j) {
            const int e = lane + j * 64;
            if (l[j] > hv) { hv = l[j]; hi = e; }
            if (t[j] > gv) { gv = t[j]; gi = e; }
        }
        #pragma unroll
        for (int off = 32; off > 0; off >>= 1) {
            float ov = __shfl_xor(hv, off); int oi = __shfl_xor(hi, off);
            if (ov > hv || (ov == hv && oi < hi)) { hv = ov; hi = oi; }
            float ov2 = __shfl_xor(gv, off); int oi2 = __shfl_xor(gi, off);
            if (ov2 > gv || (ov2 == gv && oi2 < gi)) { gv = ov2; gi = oi2; }
        }

        // softmax exps + sums
        float eh[5], eg[5];
        float sh = 0.f, sg = 0.f;
        #pragma unroll
        for (int j = 0; j < 5; ++j) {
            eh[j] = expf(l[j] - hv);
            eg[j] = expf(t[j] - gv);
            sh += eh[j]; sg += eg[j];
        }
        #pragma unroll
        for (int off = 32; off > 0; off >>= 1) {
            sh += __shfl_xor(sh, off);
            sg += __shfl_xor(sg, off);
        }
        const float ish = 1.0f / sh;
        const float isg = 1.0f / sg;

        float a_part = 0.f;
        #pragma unroll
        for (int j = 0; j < 5; ++j) {
            const int e = lane + j * 64;
            racc[j] += eh[j] * ish;
            if (e == hi) hacc[j] += 1.0f;
            if (e == gi) a_part = eg[j] * isg;
        }
        #pragma unroll
        for (int off = 32; off > 0; off >>= 1) a_part += __shfl_xor(a_part, off);
        const float yv = (1.0f - a_part) + a_part;   // straight-through value

        // cb write (overwrites logits slice in place)
        float* lrow = Lcb + (size_t)n * GE + g * EDIM;
        #pragma unroll
        for (int j = 0; j < 5; ++j) {
            const int e = lane + j * 64;
            lrow[e] = (e == gi) ? yv : 0.0f;
        }

        // quantized write: yv * entries[g, gi, :]
        const float* ent = entries + ((size_t)(g * EDIM + gi)) * DDIM;
        float* qrow = out + (size_t)n * 768 + g * DDIM;
        #pragma unroll
        for (int jj = 0; jj < 6; ++jj) {
            const int d = lane + jj * 64;
            qrow[d] = yv * ent[d];
        }

        #pragma unroll
        for (int j = 0; j < 5; ++j) { l[j] = l2[j]; gu[j] = gu2[j]; }
    }

    // block-level reduction, then one global atomic per entry per block
    __syncthreads();
    #pragma unroll
    for (int j = 0; j < 5; ++j) {
        atomicAdd(&redH[lane + j * 64], hacc[j]);
        atomicAdd(&redS[lane + j * 64], racc[j]);
    }
    __syncthreads();
    for (int e = tid; e < 320; e += 256) {
        atomicAdd(&hard_acc[g * EDIM + e], redH[e]);
        atomicAdd(&soft_acc[g * EDIM + e], redS[e]);
    }
}

// ---------------- perplexities ----------------
__global__ void vq_final_k(const float* __restrict__ hard_acc,
                           const float* __restrict__ soft_acc,
                           float* __restrict__ out)
{
    const int lane = threadIdx.x & 63;
    float code = 0.f, prob = 0.f;
    for (int g = 0; g < 2; ++g) {
        float shh = 0.f, sss = 0.f;
        #pragma unroll
        for (int j = 0; j < 5; ++j) {
            const int e = g * EDIM + lane + j * 64;
            const float ph = hard_acc[e] * (1.0f / 16384.0f);
            const float ps = soft_acc[e] * (1.0f / 16384.0f);
            shh += ph * logf(ph + 1e-7f);
            sss += ps * logf(ps + 1e-7f);
        }
        #pragma unroll
        for (int off = 32; off > 0; off >>= 1) {
            shh += __shfl_xor(shh, off);
            sss += __shfl_xor(sss, off);
        }
        code += expf(-shh);
        prob += expf(-sss);
    }
    if (threadIdx.x == 0) {
        out[SCAL_OFF + 0] = code;
        out[SCAL_OFF + 1] = prob;
    }
}

extern "C" void kernel_launch(void* const* d_in, const int* in_sizes, int n_in,
                              void* d_out, int out_size, void* d_ws, size_t ws_size,
                              hipStream_t stream) {
    const float* x       = (const float*)d_in[0];
    const float* proj_w  = (const float*)d_in[1];
    const float* proj_b  = (const float*)d_in[2];
    const float* entries = (const float*)d_in[3];
    const float* gumbel  = (const float*)d_in[4];
    float* out = (float*)d_out;
    float* acc = (float*)d_ws;                     // 1280 floats
    float* logits = out + CB_OFF;                  // logits staged in cb region
    ushort_t* Xb = (ushort_t*)(out + XB_OFF);      // bf16 X in quantized region
    ushort_t* Wb = (ushort_t*)(out + WB_OFF);      // bf16 W after it

    hipLaunchKernelGGL(vq_init_k, dim3(5), dim3(256), 0, stream, acc);
    hipLaunchKernelGGL(convert_bf16_k, dim3(4256), dim3(256), 0, stream,
                       x, proj_w, Xb, Wb);
    hipLaunchKernelGGL(gemm_mfma_k, dim3(NROWS / 128, GE / 128), dim3(256), 0, stream,
                       Xb, Wb, proj_b, logits);
    hipLaunchKernelGGL(vq_rows_k, dim3(512), dim3(256), 0, stream,
                       logits, gumbel, entries, out, acc, acc + GE);
    hipLaunchKernelGGL(vq_final_k, dim3(1), dim3(64), 0, stream,
                       acc, acc + GE, out);
}